// Round 1
// baseline (362.531 us; speedup 1.0000x reference)
//
#include <hip/hip_runtime.h>

// Problem constants (B, C, T, H, W) = (4, 8, 12, 256, 256)
#define BB 4
#define CC 8
#define TT 12
#define HH 256
#define WW 256

// Sizes in floats
#define KSP_N   (BB*CC*TT*HH*WW*2)   // 50331648
#define OMASK_N (BB*1*TT*HH*WW*1)    // 3145728
#define FPROB_N (BB*1*HH*WW*1)       // 262144

// -------- Kernel 1: per-(b,t) policy rows ------------------------------------
// One block per (b,t), 256 threads (one per w). Computes the LOUPE dynamic
// policy row: softplus-normalized prob -> budget renorm -> straight-through
// acquisition. Writes out_mask row values omv[b,t,w] = m + acq and (for
// t == T-1) normed (final_prob source) into workspace.
__global__ __launch_bounds__(256) void policy_kernel(
    const float* __restrict__ mask,     // (B,1,T,H,W,1)
    const float* __restrict__ sampler,  // (1,T,W)
    const float* __restrict__ u,        // (B,T,W)
    float* __restrict__ ws_om,          // (B*T*W)
    float* __restrict__ ws_fp)          // (B*W)
{
    const int bt = blockIdx.x;          // b*T + t
    const int b  = bt / TT;
    const int t  = bt - b * TT;
    const int w  = threadIdx.x;

    __shared__ float s1[256];
    __shared__ float s2[256];

    // m = mask[b,0,0,0,w,0]
    const float m  = mask[b * (TT * HH * WW) + w];
    const float fr = 1.0f - m;

    // softplus(SLOPE*sampler)/SLOPE, JAX form: max(x,0) + log1p(exp(-|x|))
    const float x  = 10.0f * sampler[t * WW + w];
    const float sp = (fmaxf(x, 0.0f) + log1pf(expf(-fabsf(x)))) * 0.1f;

    // denom = max_w(free * sp)
    s1[w] = fr * sp;
    __syncthreads();
    for (int s = 128; s > 0; s >>= 1) {
        if (w < s) s1[w] = fmaxf(s1[w], s1[w + s]);
        __syncthreads();
    }
    const float denom = s1[0];
    __syncthreads();

    const float prob = sp / denom;
    const float mp   = prob * fr;        // masked_prob

    // n_free = sum(free); sum(masked_prob)
    s1[w] = fr;
    s2[w] = mp;
    __syncthreads();
    for (int s = 128; s > 0; s >>= 1) {
        if (w < s) { s1[w] += s1[w + s]; s2[w] += s2[w + s]; }
        __syncthreads();
    }
    const float n_free = s1[0];
    const float xbar   = s2[0] / n_free;

    const float sparsity = 43.0f / n_free;      // BUDGET / n_free
    const float r        = sparsity / xbar;
    const float beta     = (1.0f - sparsity) / (1.0f - xbar);
    float normed = (r <= 1.0f) ? (mp * r) : (1.0f - (1.0f - mp) * beta);
    normed *= fr;

    const float uu = u[bt * WW + w];
    const float xs = 10.0f * (normed - uu);     // ST_SLOPE * (normed - u)
    float sig;
    if (xs >= 0.0f) {
        sig = 1.0f / (1.0f + expf(-xs));
    } else {
        const float e = expf(xs);
        sig = e / (1.0f + e);
    }
    const float hard = (normed > uu) ? 1.0f : 0.0f;
    const float acq  = sig + (hard - sig);      // straight-through, fp32 order

    ws_om[bt * WW + w] = m + acq;               // out_mask row value
    if (t == TT - 1) ws_fp[b * WW + w] = normed;
}

// -------- Kernel 2: masked_kspace (the 402 MB mover) -------------------------
// float4 over (B,C,T,H,W,2); each vec = 2 (w,ri) pairs, same (b,c,t,h).
__global__ __launch_bounds__(256) void mk_kernel(
    const float4* __restrict__ ks,
    const float* __restrict__ om,
    float4* __restrict__ out,
    int nv)
{
    const int stride = gridDim.x * blockDim.x;
    for (int v = blockIdx.x * blockDim.x + threadIdx.x; v < nv; v += stride) {
        const float4 k = ks[v];
        // flat float index f = 4v; pair index p = 2v over (b,c,t,h,w)
        const int w0 = (v * 2) & (WW - 1);       // even, w1 = w0+1
        const int t  = (v >> 15) % TT;           // p / (H*W) % T
        const int b  = v / (CC * TT * HH * WW / 2);  // v / 3145728
        const float* row = om + b * (TT * WW) + t * WW;
        const float o0 = row[w0];
        const float o1 = row[w0 + 1];
        float4 r;
        r.x = o0 * k.x; if (k.x < 0.0f && o0 == 0.0f) r.x = -r.x;
        r.y = o0 * k.y; if (k.y < 0.0f && o0 == 0.0f) r.y = -r.y;
        r.z = o1 * k.z; if (k.z < 0.0f && o1 == 0.0f) r.z = -r.z;
        r.w = o1 * k.w; if (k.w < 0.0f && o1 == 0.0f) r.w = -r.w;
        out[v] = r;
    }
}

// -------- Kernel 3: broadcast out_mask over H, final_prob over H -------------
__global__ __launch_bounds__(256) void bc_kernel(
    const float* __restrict__ om,     // (B*T*W)
    const float* __restrict__ fp,     // (B*W)
    float4* __restrict__ out_om,      // OMASK_N/4 vecs
    float4* __restrict__ out_fp)      // FPROB_N/4 vecs
{
    const int NV_OM = OMASK_N / 4;    // 786432
    const int NV_FP = FPROB_N / 4;    // 65536
    const int stride = gridDim.x * blockDim.x;
    for (int v = blockIdx.x * blockDim.x + threadIdx.x; v < NV_OM + NV_FP; v += stride) {
        if (v < NV_OM) {
            const int f  = v * 4;                 // flat over (B,1,T,H,W,1)
            const int w0 = f & (WW - 1);
            const int t  = (f >> 16) % TT;        // f / (H*W) % T
            const int b  = f / (TT * HH * WW);    // f / 786432
            const float* row = om + b * (TT * WW) + t * WW;
            float4 r;
            r.x = row[w0]; r.y = row[w0 + 1]; r.z = row[w0 + 2]; r.w = row[w0 + 3];
            out_om[v] = r;
        } else {
            const int v2 = v - NV_OM;
            const int f  = v2 * 4;                // flat over (B,1,H,W,1)
            const int w0 = f & (WW - 1);
            const int b  = f / (HH * WW);         // f / 65536
            const float* row = fp + b * WW;
            float4 r;
            r.x = row[w0]; r.y = row[w0 + 1]; r.z = row[w0 + 2]; r.w = row[w0 + 3];
            out_fp[v2] = r;
        }
    }
}

extern "C" void kernel_launch(void* const* d_in, const int* in_sizes, int n_in,
                              void* d_out, int out_size, void* d_ws, size_t ws_size,
                              hipStream_t stream) {
    const float* mask    = (const float*)d_in[0];
    const float* kspace  = (const float*)d_in[1];
    const float* sampler = (const float*)d_in[2];
    const float* u       = (const float*)d_in[3];
    float* out = (float*)d_out;

    float* ws_om = (float*)d_ws;             // B*T*W = 12288 floats
    float* ws_fp = ws_om + BB * TT * WW;     // B*W   = 1024 floats

    // 1) policy rows (tiny)
    policy_kernel<<<BB * TT, 256, 0, stream>>>(mask, sampler, u, ws_om, ws_fp);

    // 2) masked_kspace: 12,582,912 float4 vecs, grid-stride
    const int NV = KSP_N / 4;
    mk_kernel<<<3072, 256, 0, stream>>>((const float4*)kspace, ws_om,
                                        (float4*)out, NV);

    // 3) out_mask + final_prob broadcast
    bc_kernel<<<1024, 256, 0, stream>>>(ws_om, ws_fp,
                                        (float4*)(out + KSP_N),
                                        (float4*)(out + KSP_N + OMASK_N));
}

// Round 2
// 345.244 us; speedup vs baseline: 1.0501x; 1.0501x over previous
//
#include <hip/hip_runtime.h>

// Problem constants (B, C, T, H, W) = (4, 8, 12, 256, 256)
#define BB 4
#define CC 8
#define TT 12
#define HH 256
#define WW 256

// Sizes in floats
#define KSP_N   (BB*CC*TT*HH*WW*2)   // 50331648
#define OMASK_N (BB*1*TT*HH*WW*1)    // 3145728
#define FPROB_N (BB*1*HH*WW*1)       // 262144

// float4 vec counts
#define NV_K    (KSP_N/4)            // 12582912
#define NV_OM   (OMASK_N/4)          // 786432
#define NV_FP   (FPROB_N/4)          // 65536
#define NV_ALL  (NV_K+NV_OM+NV_FP)   // 13434880 = 52480 * 256

// -------- Kernel 1: per-(b,t) policy rows ------------------------------------
__global__ __launch_bounds__(256) void policy_kernel(
    const float* __restrict__ mask,     // (B,1,T,H,W,1)
    const float* __restrict__ sampler,  // (1,T,W)
    const float* __restrict__ u,        // (B,T,W)
    float* __restrict__ ws_om,          // (B*T*W)
    float* __restrict__ ws_fp)          // (B*W)
{
    const int bt = blockIdx.x;          // b*T + t
    const int b  = bt / TT;
    const int t  = bt - b * TT;
    const int w  = threadIdx.x;

    __shared__ float s1[256];
    __shared__ float s2[256];

    const float m  = mask[b * (TT * HH * WW) + w];
    const float fr = 1.0f - m;

    // softplus(SLOPE*x)/SLOPE, JAX form: max(x,0) + log1p(exp(-|x|))
    const float x  = 10.0f * sampler[t * WW + w];
    const float sp = (fmaxf(x, 0.0f) + log1pf(expf(-fabsf(x)))) * 0.1f;

    // denom = max_w(free * sp)
    s1[w] = fr * sp;
    __syncthreads();
    for (int s = 128; s > 0; s >>= 1) {
        if (w < s) s1[w] = fmaxf(s1[w], s1[w + s]);
        __syncthreads();
    }
    const float denom = s1[0];
    __syncthreads();

    const float prob = sp / denom;
    const float mp   = prob * fr;        // masked_prob

    s1[w] = fr;
    s2[w] = mp;
    __syncthreads();
    for (int s = 128; s > 0; s >>= 1) {
        if (w < s) { s1[w] += s1[w + s]; s2[w] += s2[w + s]; }
        __syncthreads();
    }
    const float n_free = s1[0];
    const float xbar   = s2[0] / n_free;

    const float sparsity = 43.0f / n_free;      // BUDGET / n_free
    const float r        = sparsity / xbar;
    const float beta     = (1.0f - sparsity) / (1.0f - xbar);
    float normed = (r <= 1.0f) ? (mp * r) : (1.0f - (1.0f - mp) * beta);
    normed *= fr;

    const float uu = u[bt * WW + w];
    const float xs = 10.0f * (normed - uu);     // ST_SLOPE * (normed - u)
    float sig;
    if (xs >= 0.0f) {
        sig = 1.0f / (1.0f + expf(-xs));
    } else {
        const float e = expf(xs);
        sig = e / (1.0f + e);
    }
    const float hard = (normed > uu) ? 1.0f : 0.0f;
    const float acq  = sig + (hard - sig);      // straight-through, fp32 order

    ws_om[bt * WW + w] = m + acq;               // out_mask row value
    if (t == TT - 1) ws_fp[b * WW + w] = normed;
}

// -------- Kernel 2: fused mover ----------------------------------------------
// One float4 per thread over the ENTIRE concatenated output:
//   [0, NV_K)                 masked_kspace = fix(out_mask * kspace)
//   [NV_K, NV_K+NV_OM)        out_mask broadcast over H
//   [NV_K+NV_OM, NV_ALL)      final_prob broadcast over H
// d_out regions are contiguous, so out[v] is uniform for all three.
__global__ __launch_bounds__(256) void fused_kernel(
    const float4* __restrict__ ks,
    const float* __restrict__ om,     // (B*T*W)
    const float* __restrict__ fp,     // (B*W)
    float4* __restrict__ out)
{
    const int v = blockIdx.x * 256 + threadIdx.x;

    if (v < NV_K) {
        // (B,C,T,H,W,2): each vec = 2 (w,ri) pairs, same (b,c,t,h)
        const float4 k = ks[v];
        const int idx = v >> 15;                 // (b*C + c)*T + t ; 2^15 vecs per (b,c,t)
        const int t   = idx % TT;
        const int b   = idx / (CC * TT);
        const int w0  = (v * 2) & (WW - 1);      // even; w1 = w0+1
        const float* row = om + b * (TT * WW) + t * WW;
        const float o0 = row[w0];
        const float o1 = row[w0 + 1];
        float4 r;
        r.x = o0 * k.x; if (k.x < 0.0f && o0 == 0.0f) r.x = -r.x;
        r.y = o0 * k.y; if (k.y < 0.0f && o0 == 0.0f) r.y = -r.y;
        r.z = o1 * k.z; if (k.z < 0.0f && o1 == 0.0f) r.z = -r.z;
        r.w = o1 * k.w; if (k.w < 0.0f && o1 == 0.0f) r.w = -r.w;
        out[v] = r;
    } else if (v < NV_K + NV_OM) {
        const int vv = v - NV_K;
        const int f  = vv * 4;                   // flat over (B,1,T,H,W,1)
        const int w0 = f & (WW - 1);
        const int t  = (f >> 16) % TT;           // f / (H*W) % T
        const int b  = f / (TT * HH * WW);
        const float* row = om + b * (TT * WW) + t * WW;
        float4 r;
        r.x = row[w0]; r.y = row[w0 + 1]; r.z = row[w0 + 2]; r.w = row[w0 + 3];
        out[v] = r;
    } else {
        const int vv = v - (NV_K + NV_OM);
        const int f  = vv * 4;                   // flat over (B,1,H,W,1)
        const int w0 = f & (WW - 1);
        const int b  = f >> 16;                  // f / (H*W)
        const float* row = fp + b * WW;
        float4 r;
        r.x = row[w0]; r.y = row[w0 + 1]; r.z = row[w0 + 2]; r.w = row[w0 + 3];
        out[v] = r;
    }
}

extern "C" void kernel_launch(void* const* d_in, const int* in_sizes, int n_in,
                              void* d_out, int out_size, void* d_ws, size_t ws_size,
                              hipStream_t stream) {
    const float* mask    = (const float*)d_in[0];
    const float* kspace  = (const float*)d_in[1];
    const float* sampler = (const float*)d_in[2];
    const float* u       = (const float*)d_in[3];
    float* out = (float*)d_out;

    float* ws_om = (float*)d_ws;             // B*T*W = 12288 floats
    float* ws_fp = ws_om + BB * TT * WW;     // B*W   = 1024 floats

    // 1) policy rows (tiny)
    policy_kernel<<<BB * TT, 256, 0, stream>>>(mask, sampler, u, ws_om, ws_fp);

    // 2) everything else: one float4 per thread, 52480 blocks
    fused_kernel<<<NV_ALL / 256, 256, 0, stream>>>((const float4*)kspace,
                                                   ws_om, ws_fp, (float4*)out);
}

// Round 4
// 342.296 us; speedup vs baseline: 1.0591x; 1.0086x over previous
//
#include <hip/hip_runtime.h>

// Problem constants (B, C, T, H, W) = (4, 8, 12, 256, 256)
#define BB 4
#define CC 8
#define TT 12
#define HH 256
#define WW 256

// Sizes in floats
#define KSP_N   (BB*CC*TT*HH*WW*2)   // 50331648
#define OMASK_N (BB*1*TT*HH*WW*1)    // 3145728
#define FPROB_N (BB*1*HH*WW*1)       // 262144

// float4 vec counts (all multiples of 512 -> region-uniform blocks at VPT=2)
#define NV_K    (KSP_N/4)            // 12582912 = 512*24576
#define NV_OM   (OMASK_N/4)          // 786432   = 512*1536
#define NV_FP   (FPROB_N/4)          // 65536    = 512*128
#define NV_ALL  (NV_K+NV_OM+NV_FP)   // 13434880 = 512*26240

// Native clang vector types (required by __builtin_nontemporal_*)
typedef float f4 __attribute__((ext_vector_type(4)));
typedef float f2 __attribute__((ext_vector_type(2)));

// -------- Kernel 1: per-(b,t) policy rows ------------------------------------
__global__ __launch_bounds__(256) void policy_kernel(
    const float* __restrict__ mask,     // (B,1,T,H,W,1)
    const float* __restrict__ sampler,  // (1,T,W)
    const float* __restrict__ u,        // (B,T,W)
    float* __restrict__ ws_om,          // (B*T*W)
    float* __restrict__ ws_fp)          // (B*W)
{
    const int bt = blockIdx.x;          // b*T + t
    const int b  = bt / TT;
    const int t  = bt - b * TT;
    const int w  = threadIdx.x;

    __shared__ float s1[256];
    __shared__ float s2[256];

    const float m  = mask[b * (TT * HH * WW) + w];
    const float fr = 1.0f - m;

    // softplus(SLOPE*x)/SLOPE, JAX form: max(x,0) + log1p(exp(-|x|))
    const float x  = 10.0f * sampler[t * WW + w];
    const float sp = (fmaxf(x, 0.0f) + log1pf(expf(-fabsf(x)))) * 0.1f;

    // denom = max_w(free * sp)
    s1[w] = fr * sp;
    __syncthreads();
    for (int s = 128; s > 0; s >>= 1) {
        if (w < s) s1[w] = fmaxf(s1[w], s1[w + s]);
        __syncthreads();
    }
    const float denom = s1[0];
    __syncthreads();

    const float prob = sp / denom;
    const float mp   = prob * fr;        // masked_prob

    s1[w] = fr;
    s2[w] = mp;
    __syncthreads();
    for (int s = 128; s > 0; s >>= 1) {
        if (w < s) { s1[w] += s1[w + s]; s2[w] += s2[w + s]; }
        __syncthreads();
    }
    const float n_free = s1[0];
    const float xbar   = s2[0] / n_free;

    const float sparsity = 43.0f / n_free;      // BUDGET / n_free
    const float r        = sparsity / xbar;
    const float beta     = (1.0f - sparsity) / (1.0f - xbar);
    float normed = (r <= 1.0f) ? (mp * r) : (1.0f - (1.0f - mp) * beta);
    normed *= fr;

    const float uu = u[bt * WW + w];
    const float xs = 10.0f * (normed - uu);     // ST_SLOPE * (normed - u)
    float sig;
    if (xs >= 0.0f) {
        sig = 1.0f / (1.0f + expf(-xs));
    } else {
        const float e = expf(xs);
        sig = e / (1.0f + e);
    }
    const float hard = (normed > uu) ? 1.0f : 0.0f;
    const float acq  = sig + (hard - sig);      // straight-through, fp32 order
    // note: hard==0 -> acq == 0 exactly; so om==0 iff (m==0 && hard==0)

    ws_om[bt * WW + w] = m + acq;               // out_mask row value
    if (t == TT - 1) ws_fp[b * WW + w] = normed;
}

// -------- Kernel 2: fused mover, 2 float4 per thread -------------------------
// Block covers 512 consecutive vecs of the concatenated output:
//   [0, NV_K)            masked_kspace = fix(out_mask * kspace)
//   [NV_K, +NV_OM)       out_mask broadcast over H
//   [+NV_OM, NV_ALL)     final_prob broadcast over H
// Region boundaries are multiples of 512 -> branch is block-uniform.
__device__ __forceinline__ float mkv(float o, float k) {
    // reference: (o*k) * (k<0 && o==0 ? -1 : 1). o==0 => result is +0.0.
    return (o == 0.0f) ? 0.0f : o * k;
}

__global__ __launch_bounds__(256) void fused_kernel(
    const f4* __restrict__ ks,
    const float* __restrict__ om,     // (B*T*W)
    const float* __restrict__ fp,     // (B*W)
    f4* __restrict__ out)
{
    const int v0 = blockIdx.x * 512 + threadIdx.x;   // first vec; second = v0+256

    if (v0 < NV_K) {
        // (B,C,T,H,W,2): each vec = 2 (w,ri) pairs, same (b,c,t,h)
        const f4 ka = __builtin_nontemporal_load(&ks[v0]);
        const f4 kb = __builtin_nontemporal_load(&ks[v0 + 256]);

        const int idx = v0 >> 15;                // (b*C+c)*T + t ; 2^15 vecs per (b,c,t)
        const int t   = idx % TT;
        const int b   = idx / (CC * TT);
        const float* row = om + b * (TT * WW) + t * WW;
        const int wa = (v0 * 2) & (WW - 1);      // even; +256 vecs = +512 floats = same w
        const int wb = (v0 * 2 + 512) & (WW - 1);
        const f2 oa = *(const f2*)(row + wa);
        const f2 ob = *(const f2*)(row + wb);

        f4 ra, rb;
        ra.x = mkv(oa.x, ka.x); ra.y = mkv(oa.x, ka.y);
        ra.z = mkv(oa.y, ka.z); ra.w = mkv(oa.y, ka.w);
        rb.x = mkv(ob.x, kb.x); rb.y = mkv(ob.x, kb.y);
        rb.z = mkv(ob.y, kb.z); rb.w = mkv(ob.y, kb.w);
        __builtin_nontemporal_store(ra, &out[v0]);
        __builtin_nontemporal_store(rb, &out[v0 + 256]);
    } else if (v0 < NV_K + NV_OM) {
        // out_mask broadcast: (B,1,T,H,W,1); 4 floats per vec, float4-aligned row read
        const int vv = v0 - NV_K;
        const int f  = vv * 4;
        const int w0 = f & (WW - 1);             // +256 vecs = +1024 floats = same w
        const int t  = (f >> 16) % TT;
        const int b  = f / (TT * HH * WW);
        const f4 r = *(const f4*)(om + b * (TT * WW) + t * WW + w0);
        __builtin_nontemporal_store(r, &out[v0]);
        // second vec: f+1024 -> h+4 rows later; recompute t,b in case of crossing
        const int f2v = f + 1024;
        const int t2  = (f2v >> 16) % TT;
        const int b2  = f2v / (TT * HH * WW);
        const f4 r2 = *(const f4*)(om + b2 * (TT * WW) + t2 * WW + w0);
        __builtin_nontemporal_store(r2, &out[v0 + 256]);
    } else {
        // final_prob broadcast: (B,1,H,W,1)
        const int vv = v0 - (NV_K + NV_OM);
        const int f  = vv * 4;
        const int w0 = f & (WW - 1);
        const int b  = f >> 16;
        const f4 r = *(const f4*)(fp + b * WW + w0);
        __builtin_nontemporal_store(r, &out[v0]);
        const int f2v = f + 1024;
        const int b2  = f2v >> 16;
        const f4 r2 = *(const f4*)(fp + b2 * WW + w0);
        __builtin_nontemporal_store(r2, &out[v0 + 256]);
    }
}

extern "C" void kernel_launch(void* const* d_in, const int* in_sizes, int n_in,
                              void* d_out, int out_size, void* d_ws, size_t ws_size,
                              hipStream_t stream) {
    const float* mask    = (const float*)d_in[0];
    const float* kspace  = (const float*)d_in[1];
    const float* sampler = (const float*)d_in[2];
    const float* u       = (const float*)d_in[3];
    float* out = (float*)d_out;

    float* ws_om = (float*)d_ws;             // B*T*W = 12288 floats
    float* ws_fp = ws_om + BB * TT * WW;     // B*W   = 1024 floats

    // 1) policy rows (tiny)
    policy_kernel<<<BB * TT, 256, 0, stream>>>(mask, sampler, u, ws_om, ws_fp);

    // 2) everything else: 2 float4 per thread, 26240 blocks
    fused_kernel<<<NV_ALL / 512, 256, 0, stream>>>((const f4*)kspace,
                                                   ws_om, ws_fp, (f4*)out);
}